// Round 8
// baseline (356.680 us; speedup 1.0000x reference)
//
#include <hip/hip_runtime.h>
#include <hip/hip_bf16.h>

// LGCN on MI355X, 2-launch version. N=1600, Fin=1433, GCN hidden=32,
// two LGConv blocks (+8 ch each), out 7 channels, row mask.
// K1: CSR build + mask detect + barrier init + split-K GEMM (all independent).
// K2: reduce -> spmv -> lgconv1 -> lgconv2 -> final with software grid barriers.

constexpr int NN   = 1600;
constexpr int FIN  = 1433;
constexpr int HGCN = 32;
constexpr int HE   = 48;    // h_ext row stride (32 + 8 + 8)
constexpr int NBS  = 96;    // CSR neighbor stride
constexpr float BN_EPS = 1e-3f;

constexpr int KS    = 16;
constexpr int CHUNK = 90;   // 16*90 = 1440 >= 1433
constexpr int BM    = 32;
constexpr int SXS   = 92;
constexpr int RB    = NN / BM;            // 50 row-blocks
constexpr int CSRB  = 400;                // csr blocks (4 rows each)
constexpr int K1B   = CSRB + 1 + RB * KS; // 1201
constexpr int K2B   = 256;                // must be <= #CUs for barrier safety

// ---------------- software grid barrier (device scope) -------------------------
__device__ __forceinline__ void gbar(int* bar, int idx) {
    __syncthreads();
    __threadfence();                       // release: L2 writeback (agent scope)
    if (threadIdx.x == 0) {
        __hip_atomic_fetch_add(&bar[idx], 1, __ATOMIC_RELAXED, __HIP_MEMORY_SCOPE_AGENT);
        while (__hip_atomic_load(&bar[idx], __ATOMIC_RELAXED, __HIP_MEMORY_SCOPE_AGENT) < K2B) {
            __builtin_amdgcn_s_sleep(2);
        }
    }
    __syncthreads();
    __threadfence();                       // acquire: L2 invalidate
}

// ================= K1: csr + mask/barrier-init + gemm tiles ====================
__global__ __launch_bounds__(256) void k1(const float* __restrict__ x,
                                          const float* __restrict__ W0,
                                          const float* __restrict__ adj,
                                          int* __restrict__ deg,
                                          unsigned short* __restrict__ nbr,
                                          const unsigned char* __restrict__ mb,
                                          int* __restrict__ flag,
                                          int* __restrict__ bar,
                                          float* __restrict__ hp) {
    __shared__ float sx[BM][SXS];
    __shared__ float sw[CHUNK * HGCN];
    int b = blockIdx.x, t = threadIdx.x;

    if (b < CSRB) {                        // ---- CSR build: 4 waves, 1 row each
        int lane = t & 63;
        int row  = b * 4 + (t >> 6);
        const float*  ar  = adj + (size_t)row * NN;
        const float4* ar4 = (const float4*)ar;
        unsigned short* nb = nbr + (size_t)row * NBS;
        int cnt = 0;
        #pragma unroll
        for (int it = 0; it < 6; ++it) {   // 6*256 = 1536 elements
            float4 v = ar4[it * 64 + lane];
            int base = it * 256 + 4 * lane;
            #pragma unroll
            for (int c = 0; c < 4; ++c) {
                float vc = (c == 0) ? v.x : (c == 1) ? v.y : (c == 2) ? v.z : v.w;
                bool p = (vc != 0.0f);
                unsigned long long m = __ballot(p);
                if (p) {
                    int off = cnt + __popcll(m & ((1ull << lane) - 1ull));
                    if (off < NBS) nb[off] = (unsigned short)(base + c);
                }
                cnt += __popcll(m);
            }
        }
        {                                  // tail 64
            float v = ar[1536 + lane];
            bool p = (v != 0.0f);
            unsigned long long m = __ballot(p);
            if (p) {
                int off = cnt + __popcll(m & ((1ull << lane) - 1ull));
                if (off < NBS) nb[off] = (unsigned short)(1536 + lane);
            }
            cnt += __popcll(m);
        }
        if (lane == 0) deg[row] = cnt < NBS ? cnt : NBS;
        return;
    }

    if (b == CSRB) {                       // ---- barrier init + mask detect
        if (t < 8) bar[t] = 0;
        if (t < 64) {
            int lane = t;
            bool odd = false, flt = false;
            for (int i = lane; i < NN; i += 64) {
                unsigned char v = mb[i];
                if (v) {
                    int r = i & 3;
                    if (r != 0) odd = true;
                    if (r >= 2 && (v == 0x3F || v == 0x80)) flt = true;  // 1.0f pattern
                }
            }
            unsigned long long mo = __ballot(odd);
            unsigned long long mf = __ballot(flt);
            if (lane == 0) *flag = mf ? 2 : (mo ? 1 : 0);  // 2=f32, 1=u8, 0=i32
        }
        return;
    }

    // ---- GEMM tile: h0 partial = x[rb-block] @ W0[k-chunk]
    int tile = b - (CSRB + 1);
    int rb   = tile % RB;
    int ks   = tile / RB;
    int lane = t & 31;
    int row0 = rb * BM;
    int k0   = ks * CHUNK;
    int vk   = FIN - k0; if (vk > CHUNK) vk = CHUNK;

    {
        int g = t >> 5;
        #pragma unroll
        for (int j = 0; j < 4; ++j) {
            int r = g + 8 * j;
            const float* xr = x + (size_t)(row0 + r) * FIN + k0;
            #pragma unroll
            for (int m = 0; m < 3; ++m) {
                int k = lane + 32 * m;
                if (k < CHUNK) sx[r][k] = (k < vk) ? xr[k] : 0.0f;
            }
        }
    }
    {
        const float4* w4  = (const float4*)(W0 + (size_t)k0 * HGCN);
        float4*       sw4 = (float4*)sw;
        int vf4 = vk * 8;
        for (int i = t; i < CHUNK * 8; i += 256)
            sw4[i] = (i < vf4) ? w4[i] : make_float4(0.f, 0.f, 0.f, 0.f);
    }
    __syncthreads();

    int col = lane;
    int rq  = t >> 5;
    float acc0 = 0.f, acc1 = 0.f, acc2 = 0.f, acc3 = 0.f;
    #pragma unroll 4
    for (int kk = 0; kk < 88; kk += 4) {
        float4 a0 = *(const float4*)&sx[rq     ][kk];
        float4 a1 = *(const float4*)&sx[rq +  8][kk];
        float4 a2 = *(const float4*)&sx[rq + 16][kk];
        float4 a3 = *(const float4*)&sx[rq + 24][kk];
        float w0v = sw[(kk + 0) * HGCN + col];
        float w1v = sw[(kk + 1) * HGCN + col];
        float w2v = sw[(kk + 2) * HGCN + col];
        float w3v = sw[(kk + 3) * HGCN + col];
        acc0 += a0.x * w0v + a0.y * w1v + a0.z * w2v + a0.w * w3v;
        acc1 += a1.x * w0v + a1.y * w1v + a1.z * w2v + a1.w * w3v;
        acc2 += a2.x * w0v + a2.y * w1v + a2.z * w2v + a2.w * w3v;
        acc3 += a3.x * w0v + a3.y * w1v + a3.z * w2v + a3.w * w3v;
    }
    #pragma unroll
    for (int kk = 88; kk < CHUNK; ++kk) {
        float wv = sw[kk * HGCN + col];
        acc0 += sx[rq     ][kk] * wv;
        acc1 += sx[rq +  8][kk] * wv;
        acc2 += sx[rq + 16][kk] * wv;
        acc3 += sx[rq + 24][kk] * wv;
    }

    float* o = hp + (size_t)ks * NN * HGCN + (size_t)(row0 + rq) * HGCN + col;
    o[0 * 8 * HGCN] = acc0;
    o[1 * 8 * HGCN] = acc1;
    o[2 * 8 * HGCN] = acc2;
    o[3 * 8 * HGCN] = acc3;
}

// ================= K2 phases ====================================================
template<int F, int MID>
__device__ __forceinline__ void lgconv_phase(int b, int wave, int lane, int t,
        const int* __restrict__ deg, const unsigned short* __restrict__ nbr,
        const float* __restrict__ Wa, const float* __restrict__ Wb,
        const float* __restrict__ g, const float* __restrict__ bb,
        const float* __restrict__ mm, const float* __restrict__ vv,
        float* __restrict__ he, float* sWa, float* T, float* C1) {
    {                                       // stage Wa (5*F*MID floats, %4==0)
        const float4* w4 = (const float4*)Wa;
        float4*       s4 = (float4*)sWa;
        for (int i = t; i < 5 * F * MID / 4; i += 512) s4[i] = w4[i];
    }
    __syncthreads();

    int row = b * 8 + wave;
    bool act = row < NN;
    int d = 0;
    const unsigned short* nb = nullptr;
    if (act) { d = deg[row]; nb = nbr + (size_t)row * NBS; }

    if (act && lane < F) {                  // topk bubble (8 largest positives)
        float t0=0.f,t1=0.f,t2=0.f,t3=0.f,t4=0.f,t5=0.f,t6=0.f,t7=0.f;
        for (int it = 0; it < d; ++it) {
            float val = he[(int)nb[it] * HE + lane];
            float c;
            c = t0; t0 = fmaxf(c, val); val = fminf(c, val);
            c = t1; t1 = fmaxf(c, val); val = fminf(c, val);
            c = t2; t2 = fmaxf(c, val); val = fminf(c, val);
            c = t3; t3 = fmaxf(c, val); val = fminf(c, val);
            c = t4; t4 = fmaxf(c, val); val = fminf(c, val);
            c = t5; t5 = fmaxf(c, val); val = fminf(c, val);
            c = t6; t6 = fmaxf(c, val); val = fminf(c, val);
            c = t7; t7 = fmaxf(c, val); val = fminf(c, val);
        }
        T[0*F+lane] = he[row * HE + lane];  // own feature first
        T[1*F+lane] = t0; T[2*F+lane] = t1; T[3*F+lane] = t2; T[4*F+lane] = t3;
        T[5*F+lane] = t4; T[6*F+lane] = t5; T[7*F+lane] = t6; T[8*F+lane] = t7;
    }
    __syncthreads();

    if (act) {                              // conv1
        for (int oi = lane; oi < 5 * MID; oi += 64) {
            int p = oi / MID, o = oi - p * MID;
            float acc = 0.f;
            #pragma unroll
            for (int kw = 0; kw < 5; ++kw) {
                const float* w  = &sWa[kw * F * MID + o];
                const float* tt = &T[(p + kw) * F];
                for (int ci = 0; ci < F; ++ci)
                    acc += tt[ci] * w[ci * MID];
            }
            C1[p * MID + o] = acc;
        }
    }
    __syncthreads();

    if (act && lane < 8) {                  // conv2 pos-0 + BN
        float acc = 0.f;
        #pragma unroll
        for (int kw = 0; kw < 5; ++kw)
            for (int ci = 0; ci < MID; ++ci)
                acc += C1[kw * MID + ci] * Wb[(kw * MID + ci) * 8 + lane];
        float y = g[lane] * (acc - mm[lane]) * rsqrtf(vv[lane] + BN_EPS) + bb[lane];
        he[row * HE + F + lane] = y;
    }
}

__global__ __launch_bounds__(512) void k2(
        const int* __restrict__ deg, const unsigned short* __restrict__ nbr,
        const float* __restrict__ hp, float* __restrict__ h0, float* __restrict__ he,
        const float* __restrict__ W1a, const float* __restrict__ W1b,
        const float* __restrict__ g1, const float* __restrict__ b1,
        const float* __restrict__ m1, const float* __restrict__ v1,
        const float* __restrict__ W2a, const float* __restrict__ W2b,
        const float* __restrict__ g2, const float* __restrict__ b2,
        const float* __restrict__ m2, const float* __restrict__ v2,
        const float* __restrict__ Wout, const void* __restrict__ mask,
        const int* __restrict__ flag, int* __restrict__ bar,
        float* __restrict__ out) {
    __shared__ float sWa[4800];             // max(5*32*20, 5*40*24)
    __shared__ float T [8][9 * 40];
    __shared__ float C1[8][5 * 24];
    __shared__ float sfin[8][HE];
    int t = threadIdx.x, b = blockIdx.x;
    int wave = t >> 6, lane = t & 63;

    // ---- phase R: h0 = sum of split-K partials (deterministic order)
    {
        int gid = b * 512 + t;
        if (gid < NN * HGCN) {
            float s = 0.f;
            #pragma unroll
            for (int k = 0; k < KS; ++k) s += hp[(size_t)k * NN * HGCN + gid];
            h0[gid] = s;
        }
    }
    gbar(bar, 0);

    // ---- phase S: he[:,0:32] = adj @ h0 (CSR gather)
    {
        int grp = b * 16 + (t >> 5);
        if (grp < NN) {
            int f = t & 31;
            int d = deg[grp];
            const unsigned short* nb = nbr + (size_t)grp * NBS;
            float acc = 0.f;
            int it = 0;
            for (; it + 2 <= d; it += 2) {
                int n0 = nb[it], n1 = nb[it + 1];
                acc += h0[n0 * HGCN + f] + h0[n1 * HGCN + f];
            }
            if (it < d) acc += h0[(int)nb[it] * HGCN + f];
            he[grp * HE + f] = acc;
        }
    }
    gbar(bar, 1);

    lgconv_phase<32, 20>(b, wave, lane, t, deg, nbr, W1a, W1b, g1, b1, m1, v1,
                         he, sWa, T[wave], C1[wave]);
    gbar(bar, 2);

    lgconv_phase<40, 24>(b, wave, lane, t, deg, nbr, W2a, W2b, g2, b2, m2, v2,
                         he, sWa, T[wave], C1[wave]);
    gbar(bar, 3);

    // ---- phase F: out = mask * ((adj @ he) @ Wout)
    {
        int row = b * 8 + wave;
        bool act = row < NN;
        int d = 0;
        const unsigned short* nb = nullptr;
        if (act) { d = deg[row]; nb = nbr + (size_t)row * NBS; }
        if (act && lane < HE) {
            float acc = 0.f;
            for (int it = 0; it < d; ++it)
                acc += he[(int)nb[it] * HE + lane];
            sfin[wave][lane] = acc;
        }
        __syncthreads();
        if (act && lane < 7) {
            float acc = 0.f;
            #pragma unroll
            for (int k = 0; k < HE; ++k) acc += sfin[wave][k] * Wout[k * 7 + lane];
            int fl = *flag;
            bool mk;
            if (fl == 2)      mk = ((const float*)mask)[row] != 0.0f;
            else if (fl == 1) mk = ((const unsigned char*)mask)[row] != 0;
            else              mk = ((const int*)mask)[row] != 0;
            out[row * 7 + lane] = mk ? acc : 0.0f;
        }
    }
}

extern "C" void kernel_launch(void* const* d_in, const int* in_sizes, int n_in,
                              void* d_out, int out_size, void* d_ws, size_t ws_size,
                              hipStream_t stream) {
    const float* x    = (const float*)d_in[0];
    const float* adj  = (const float*)d_in[1];
    const float* W0   = (const float*)d_in[2];
    const float* W1a  = (const float*)d_in[3];
    const float* W1b  = (const float*)d_in[4];
    const float* W2a  = (const float*)d_in[5];
    const float* W2b  = (const float*)d_in[6];
    const float* Wout = (const float*)d_in[7];
    const float* g1 = (const float*)d_in[8];
    const float* b1 = (const float*)d_in[9];
    const float* m1 = (const float*)d_in[10];
    const float* v1 = (const float*)d_in[11];
    const float* g2 = (const float*)d_in[12];
    const float* b2 = (const float*)d_in[13];
    const float* m2 = (const float*)d_in[14];
    const float* v2 = (const float*)d_in[15];
    const void*  mask = d_in[16];

    char* ws = (char*)d_ws;
    int*            flag = (int*)(ws + 0);
    int*            bar  = (int*)(ws + 64);                 // 8 ints
    int*            deg  = (int*)(ws + 256);                // 6400 B
    unsigned short* nbr  = (unsigned short*)(ws + 8192);    // 307200 B
    float*          h0   = (float*)(ws + 315392);           // 204800 B
    float*          he   = (float*)(ws + 520192);           // 307200 B
    float*          hp   = (float*)(ws + 827392);           // 16*204800 = 3.3 MB

    float* out = (float*)d_out;

    k1<<<K1B, 256, 0, stream>>>(x, W0, adj, deg, nbr,
                                (const unsigned char*)mask, flag, bar, hp);
    k2<<<K2B, 512, 0, stream>>>(deg, nbr, hp, h0, he,
                                W1a, W1b, g1, b1, m1, v1,
                                W2a, W2b, g2, b2, m2, v2,
                                Wout, mask, flag, bar, out);
}

// Round 9
// 93.877 us; speedup vs baseline: 3.7994x; 3.7994x over previous
//
#include <hip/hip_runtime.h>
#include <hip/hip_bf16.h>

// LGCN on MI355X, 2-launch version. N=1600, Fin=1433, GCN hidden=32,
// two LGConv blocks (+8 ch each), out 7 channels, row mask.
// K1: CSR build + mask detect + barrier init + split-K GEMM (all independent).
// K2: reduce -> spmv -> lgconv1 -> lgconv2 -> final. Cross-block data uses
// agent-scope relaxed atomics (sc1, MALL-coherent) -> NO threadfence/L2 flush.

constexpr int NN   = 1600;
constexpr int FIN  = 1433;
constexpr int HGCN = 32;
constexpr int HE   = 48;    // h_ext row stride (32 + 8 + 8)
constexpr int NBS  = 96;    // CSR neighbor stride
constexpr float BN_EPS = 1e-3f;

constexpr int KS    = 16;
constexpr int CHUNK = 90;   // 16*90 = 1440 >= 1433
constexpr int BM    = 32;
constexpr int SXS   = 92;
constexpr int RB    = NN / BM;            // 50 row-blocks
constexpr int CSRB  = 400;                // csr blocks (4 rows each)
constexpr int K1B   = CSRB + 1 + RB * KS; // 1201
constexpr int K2B   = 256;                // <= #CUs (LDS 36KB -> 4 blk/CU: co-resident)

// ---------------- agent-coherent (cross-XCD) scalar access ---------------------
__device__ __forceinline__ float aload(const float* p) {
    return __hip_atomic_load(p, __ATOMIC_RELAXED, __HIP_MEMORY_SCOPE_AGENT);
}
__device__ __forceinline__ void astore(float* p, float v) {
    __hip_atomic_store(p, v, __ATOMIC_RELAXED, __HIP_MEMORY_SCOPE_AGENT);
}

// ---------------- fence-free grid barrier --------------------------------------
// __syncthreads() drains each wave's vmcnt (compiler emits s_waitcnt vmcnt(0)
// before s_barrier), so all of this block's sc1 stores are MALL-visible before
// the counter bump. Spin is a relaxed agent atomic load (proven coherent in R8).
__device__ __forceinline__ void gbar(int* bar, int idx) {
    __syncthreads();
    if (threadIdx.x == 0) {
        __hip_atomic_fetch_add(&bar[idx], 1, __ATOMIC_RELAXED, __HIP_MEMORY_SCOPE_AGENT);
        while (__hip_atomic_load(&bar[idx], __ATOMIC_RELAXED, __HIP_MEMORY_SCOPE_AGENT) < K2B)
            __builtin_amdgcn_s_sleep(4);
    }
    __syncthreads();
}

// ================= K1: csr + mask/barrier-init + gemm tiles ====================
__global__ __launch_bounds__(256) void k1(const float* __restrict__ x,
                                          const float* __restrict__ W0,
                                          const float* __restrict__ adj,
                                          int* __restrict__ deg,
                                          unsigned short* __restrict__ nbr,
                                          const unsigned char* __restrict__ mb,
                                          int* __restrict__ flag,
                                          int* __restrict__ bar,
                                          float* __restrict__ hp) {
    __shared__ float sx[BM][SXS];
    __shared__ float sw[CHUNK * HGCN];
    int b = blockIdx.x, t = threadIdx.x;

    if (b < CSRB) {                        // ---- CSR build: 4 waves, 1 row each
        int lane = t & 63;
        int row  = b * 4 + (t >> 6);
        const float*  ar  = adj + (size_t)row * NN;
        const float4* ar4 = (const float4*)ar;
        unsigned short* nb = nbr + (size_t)row * NBS;
        int cnt = 0;
        #pragma unroll
        for (int it = 0; it < 6; ++it) {   // 6*256 = 1536 elements
            float4 v = ar4[it * 64 + lane];
            int base = it * 256 + 4 * lane;
            #pragma unroll
            for (int c = 0; c < 4; ++c) {
                float vc = (c == 0) ? v.x : (c == 1) ? v.y : (c == 2) ? v.z : v.w;
                bool p = (vc != 0.0f);
                unsigned long long m = __ballot(p);
                if (p) {
                    int off = cnt + __popcll(m & ((1ull << lane) - 1ull));
                    if (off < NBS) nb[off] = (unsigned short)(base + c);
                }
                cnt += __popcll(m);
            }
        }
        {                                  // tail 64
            float v = ar[1536 + lane];
            bool p = (v != 0.0f);
            unsigned long long m = __ballot(p);
            if (p) {
                int off = cnt + __popcll(m & ((1ull << lane) - 1ull));
                if (off < NBS) nb[off] = (unsigned short)(1536 + lane);
            }
            cnt += __popcll(m);
        }
        if (lane == 0) deg[row] = cnt < NBS ? cnt : NBS;
        return;
    }

    if (b == CSRB) {                       // ---- barrier init + mask detect
        if (t < 8) bar[t] = 0;
        if (t < 64) {
            int lane = t;
            bool odd = false, flt = false;
            for (int i = lane; i < NN; i += 64) {
                unsigned char v = mb[i];
                if (v) {
                    int r = i & 3;
                    if (r != 0) odd = true;
                    if (r >= 2 && (v == 0x3F || v == 0x80)) flt = true;  // 1.0f pattern
                }
            }
            unsigned long long mo = __ballot(odd);
            unsigned long long mf = __ballot(flt);
            if (lane == 0) *flag = mf ? 2 : (mo ? 1 : 0);  // 2=f32, 1=u8, 0=i32
        }
        return;
    }

    // ---- GEMM tile: h0 partial = x[rb-block] @ W0[k-chunk]
    int tile = b - (CSRB + 1);
    int rb   = tile % RB;
    int ks   = tile / RB;
    int lane = t & 31;
    int row0 = rb * BM;
    int k0   = ks * CHUNK;
    int vk   = FIN - k0; if (vk > CHUNK) vk = CHUNK;

    {
        int g = t >> 5;
        #pragma unroll
        for (int j = 0; j < 4; ++j) {
            int r = g + 8 * j;
            const float* xr = x + (size_t)(row0 + r) * FIN + k0;
            #pragma unroll
            for (int m = 0; m < 3; ++m) {
                int k = lane + 32 * m;
                if (k < CHUNK) sx[r][k] = (k < vk) ? xr[k] : 0.0f;
            }
        }
    }
    {
        const float4* w4  = (const float4*)(W0 + (size_t)k0 * HGCN);
        float4*       sw4 = (float4*)sw;
        int vf4 = vk * 8;
        for (int i = t; i < CHUNK * 8; i += 256)
            sw4[i] = (i < vf4) ? w4[i] : make_float4(0.f, 0.f, 0.f, 0.f);
    }
    __syncthreads();

    int col = lane;
    int rq  = t >> 5;
    float acc0 = 0.f, acc1 = 0.f, acc2 = 0.f, acc3 = 0.f;
    #pragma unroll 4
    for (int kk = 0; kk < 88; kk += 4) {
        float4 a0 = *(const float4*)&sx[rq     ][kk];
        float4 a1 = *(const float4*)&sx[rq +  8][kk];
        float4 a2 = *(const float4*)&sx[rq + 16][kk];
        float4 a3 = *(const float4*)&sx[rq + 24][kk];
        float w0v = sw[(kk + 0) * HGCN + col];
        float w1v = sw[(kk + 1) * HGCN + col];
        float w2v = sw[(kk + 2) * HGCN + col];
        float w3v = sw[(kk + 3) * HGCN + col];
        acc0 += a0.x * w0v + a0.y * w1v + a0.z * w2v + a0.w * w3v;
        acc1 += a1.x * w0v + a1.y * w1v + a1.z * w2v + a1.w * w3v;
        acc2 += a2.x * w0v + a2.y * w1v + a2.z * w2v + a2.w * w3v;
        acc3 += a3.x * w0v + a3.y * w1v + a3.z * w2v + a3.w * w3v;
    }
    #pragma unroll
    for (int kk = 88; kk < CHUNK; ++kk) {
        float wv = sw[kk * HGCN + col];
        acc0 += sx[rq     ][kk] * wv;
        acc1 += sx[rq +  8][kk] * wv;
        acc2 += sx[rq + 16][kk] * wv;
        acc3 += sx[rq + 24][kk] * wv;
    }

    float* o = hp + (size_t)ks * NN * HGCN + (size_t)(row0 + rq) * HGCN + col;
    o[0 * 8 * HGCN] = acc0;
    o[1 * 8 * HGCN] = acc1;
    o[2 * 8 * HGCN] = acc2;
    o[3 * 8 * HGCN] = acc3;
}

// ================= K2 phases ====================================================
template<int F, int MID>
__device__ __forceinline__ void lgconv_phase(int b, int wave, int lane, int t,
        const int* __restrict__ deg, const unsigned short* __restrict__ nbr,
        const float* __restrict__ Wa, const float* __restrict__ Wb,
        const float* __restrict__ g, const float* __restrict__ bb,
        const float* __restrict__ mm, const float* __restrict__ vv,
        float* __restrict__ he, float* sWa, float* T, float* C1) {
    {                                       // stage Wa (5*F*MID floats, %4==0)
        const float4* w4 = (const float4*)Wa;
        float4*       s4 = (float4*)sWa;
        for (int i = t; i < 5 * F * MID / 4; i += 512) s4[i] = w4[i];
    }
    __syncthreads();

    int row = b * 8 + wave;
    bool act = row < NN;
    int d = 0;
    const unsigned short* nb = nullptr;
    if (act) { d = deg[row]; nb = nbr + (size_t)row * NBS; }

    if (act && lane < F) {                  // topk bubble (8 largest positives)
        float t0=0.f,t1=0.f,t2=0.f,t3=0.f,t4=0.f,t5=0.f,t6=0.f,t7=0.f;
        for (int it = 0; it < d; ++it) {
            float val = aload(&he[(int)nb[it] * HE + lane]);
            float c;
            c = t0; t0 = fmaxf(c, val); val = fminf(c, val);
            c = t1; t1 = fmaxf(c, val); val = fminf(c, val);
            c = t2; t2 = fmaxf(c, val); val = fminf(c, val);
            c = t3; t3 = fmaxf(c, val); val = fminf(c, val);
            c = t4; t4 = fmaxf(c, val); val = fminf(c, val);
            c = t5; t5 = fmaxf(c, val); val = fminf(c, val);
            c = t6; t6 = fmaxf(c, val); val = fminf(c, val);
            c = t7; t7 = fmaxf(c, val); val = fminf(c, val);
        }
        T[0*F+lane] = aload(&he[row * HE + lane]);  // own feature first
        T[1*F+lane] = t0; T[2*F+lane] = t1; T[3*F+lane] = t2; T[4*F+lane] = t3;
        T[5*F+lane] = t4; T[6*F+lane] = t5; T[7*F+lane] = t6; T[8*F+lane] = t7;
    }
    __syncthreads();

    if (act) {                              // conv1
        for (int oi = lane; oi < 5 * MID; oi += 64) {
            int p = oi / MID, o = oi - p * MID;
            float acc = 0.f;
            #pragma unroll
            for (int kw = 0; kw < 5; ++kw) {
                const float* w  = &sWa[kw * F * MID + o];
                const float* tt = &T[(p + kw) * F];
                for (int ci = 0; ci < F; ++ci)
                    acc += tt[ci] * w[ci * MID];
            }
            C1[p * MID + o] = acc;
        }
    }
    __syncthreads();

    if (act && lane < 8) {                  // conv2 pos-0 + BN
        float acc = 0.f;
        #pragma unroll
        for (int kw = 0; kw < 5; ++kw)
            for (int ci = 0; ci < MID; ++ci)
                acc += C1[kw * MID + ci] * Wb[(kw * MID + ci) * 8 + lane];
        float y = g[lane] * (acc - mm[lane]) * rsqrtf(vv[lane] + BN_EPS) + bb[lane];
        astore(&he[row * HE + F + lane], y);
    }
}

__global__ __launch_bounds__(512) void k2(
        const int* __restrict__ deg, const unsigned short* __restrict__ nbr,
        const float* __restrict__ hp, float* __restrict__ h0, float* __restrict__ he,
        const float* __restrict__ W1a, const float* __restrict__ W1b,
        const float* __restrict__ g1, const float* __restrict__ b1,
        const float* __restrict__ m1, const float* __restrict__ v1,
        const float* __restrict__ W2a, const float* __restrict__ W2b,
        const float* __restrict__ g2, const float* __restrict__ b2,
        const float* __restrict__ m2, const float* __restrict__ v2,
        const float* __restrict__ Wout, const void* __restrict__ mask,
        const int* __restrict__ flag, int* __restrict__ bar,
        float* __restrict__ out) {
    __shared__ float sWa[4800];             // max(5*32*20, 5*40*24)
    __shared__ float T [8][9 * 40];
    __shared__ float C1[8][5 * 24];
    __shared__ float sfin[8][HE];
    int t = threadIdx.x, b = blockIdx.x;
    int wave = t >> 6, lane = t & 63;

    // ---- phase R: h0 = sum of split-K partials (deterministic order)
    {
        int gid = b * 512 + t;
        if (gid < NN * HGCN) {
            float s = 0.f;
            #pragma unroll
            for (int k = 0; k < KS; ++k) s += hp[(size_t)k * NN * HGCN + gid];
            astore(&h0[gid], s);
        }
    }
    gbar(bar, 0);

    // ---- phase S: he[:,0:32] = adj @ h0 (CSR gather)
    {
        int grp = b * 16 + (t >> 5);
        if (grp < NN) {
            int f = t & 31;
            int d = deg[grp];
            const unsigned short* nb = nbr + (size_t)grp * NBS;
            float acc = 0.f;
            int it = 0;
            for (; it + 2 <= d; it += 2) {
                int n0 = nb[it], n1 = nb[it + 1];
                acc += aload(&h0[n0 * HGCN + f]) + aload(&h0[n1 * HGCN + f]);
            }
            if (it < d) acc += aload(&h0[(int)nb[it] * HGCN + f]);
            astore(&he[grp * HE + f], acc);
        }
    }
    gbar(bar, 1);

    lgconv_phase<32, 20>(b, wave, lane, t, deg, nbr, W1a, W1b, g1, b1, m1, v1,
                         he, sWa, T[wave], C1[wave]);
    gbar(bar, 2);

    lgconv_phase<40, 24>(b, wave, lane, t, deg, nbr, W2a, W2b, g2, b2, m2, v2,
                         he, sWa, T[wave], C1[wave]);
    gbar(bar, 3);

    // ---- phase F: out = mask * ((adj @ he) @ Wout)
    {
        int row = b * 8 + wave;
        bool act = row < NN;
        int d = 0;
        const unsigned short* nb = nullptr;
        if (act) { d = deg[row]; nb = nbr + (size_t)row * NBS; }
        if (act && lane < HE) {
            float acc = 0.f;
            for (int it = 0; it < d; ++it)
                acc += aload(&he[(int)nb[it] * HE + lane]);
            sfin[wave][lane] = acc;
        }
        __syncthreads();
        if (act && lane < 7) {
            float acc = 0.f;
            #pragma unroll
            for (int k = 0; k < HE; ++k) acc += sfin[wave][k] * Wout[k * 7 + lane];
            int fl = *flag;
            bool mk;
            if (fl == 2)      mk = ((const float*)mask)[row] != 0.0f;
            else if (fl == 1) mk = ((const unsigned char*)mask)[row] != 0;
            else              mk = ((const int*)mask)[row] != 0;
            out[row * 7 + lane] = mk ? acc : 0.0f;
        }
    }
}

extern "C" void kernel_launch(void* const* d_in, const int* in_sizes, int n_in,
                              void* d_out, int out_size, void* d_ws, size_t ws_size,
                              hipStream_t stream) {
    const float* x    = (const float*)d_in[0];
    const float* adj  = (const float*)d_in[1];
    const float* W0   = (const float*)d_in[2];
    const float* W1a  = (const float*)d_in[3];
    const float* W1b  = (const float*)d_in[4];
    const float* W2a  = (const float*)d_in[5];
    const float* W2b  = (const float*)d_in[6];
    const float* Wout = (const float*)d_in[7];
    const float* g1 = (const float*)d_in[8];
    const float* b1 = (const float*)d_in[9];
    const float* m1 = (const float*)d_in[10];
    const float* v1 = (const float*)d_in[11];
    const float* g2 = (const float*)d_in[12];
    const float* b2 = (const float*)d_in[13];
    const float* m2 = (const float*)d_in[14];
    const float* v2 = (const float*)d_in[15];
    const void*  mask = d_in[16];

    char* ws = (char*)d_ws;
    int*            flag = (int*)(ws + 0);
    int*            bar  = (int*)(ws + 64);                 // 8 ints
    int*            deg  = (int*)(ws + 256);                // 6400 B
    unsigned short* nbr  = (unsigned short*)(ws + 8192);    // 307200 B
    float*          h0   = (float*)(ws + 315392);           // 204800 B
    float*          he   = (float*)(ws + 520192);           // 307200 B
    float*          hp   = (float*)(ws + 827392);           // 16*204800 = 3.3 MB

    float* out = (float*)d_out;

    k1<<<K1B, 256, 0, stream>>>(x, W0, adj, deg, nbr,
                                (const unsigned char*)mask, flag, bar, hp);
    k2<<<K2B, 512, 0, stream>>>(deg, nbr, hp, h0, he,
                                W1a, W1b, g1, b1, m1, v1,
                                W2a, W2b, g2, b2, m2, v2,
                                Wout, mask, flag, bar, out);
}

// Round 10
// 72.690 us; speedup vs baseline: 4.9068x; 1.2915x over previous
//
#include <hip/hip_runtime.h>
#include <hip/hip_bf16.h>

// LGCN on MI355X, 2-launch version. N=1600, Fin=1433, GCN hidden=32,
// two LGConv blocks (+8 ch each), out 7 channels, row mask.
// K1: CSR build + mask detect + barrier init + split-K GEMM (all independent).
// K2: reduce -> spmv -> lgconv1 -> lgconv2 -> final.
//   Cross-block writes: agent-scope relaxed atomic stores (sc1 -> MALL).
//   Cross-block reads:  NORMAL cached loads (safe: per-buffer, no address is
//   read before its producer phase in the same run; separate line-aligned
//   buffers h0/h32/c1/c2; kernel-end release flushes L2 between launches).
//   Grid barrier: 32-slot strided arrival counters + single release flag.

constexpr int NN   = 1600;
constexpr int FIN  = 1433;
constexpr int HGCN = 32;
constexpr int NBS  = 96;    // CSR neighbor stride
constexpr float BN_EPS = 1e-3f;

constexpr int KS    = 16;
constexpr int CHUNK = 90;   // 16*90 = 1440 >= 1433
constexpr int BM    = 32;
constexpr int SXS   = 92;
constexpr int RB    = NN / BM;            // 50 row-blocks
constexpr int CSRB  = 400;                // csr blocks (4 rows each)
constexpr int K1B   = CSRB + 1 + RB * KS; // 1201
constexpr int K2B   = 256;                // <= #CUs (LDS 36KB -> co-resident)

// ---------------- agent-coherent (cross-XCD) store -----------------------------
__device__ __forceinline__ void astore(float* p, float v) {
    __hip_atomic_store(p, v, __ATOMIC_RELAXED, __HIP_MEMORY_SCOPE_AGENT);
}

// ---------------- tree grid barrier (no fences, spread arrivals) ---------------
// cnt: 4 phases x 32 slots, each slot on its own 128B line (stride 32 ints).
// rel: 4 release flags. Arrivals: 8 adds per slot (parallel lines). Block 0
// wave 0 polls the 32 slots, then sets rel[phase]; all others spin on rel.
__device__ __forceinline__ void gbar(int* cnt, int* rel, int phase) {
    __syncthreads();
    if (blockIdx.x == 0) {
        if (threadIdx.x == 0)
            __hip_atomic_fetch_add(&cnt[phase * 1024], 1,
                                   __ATOMIC_RELAXED, __HIP_MEMORY_SCOPE_AGENT);
        if (threadIdx.x < 32) {
            int* slot = &cnt[phase * 1024 + threadIdx.x * 32];
            while (__hip_atomic_load(slot, __ATOMIC_RELAXED,
                                     __HIP_MEMORY_SCOPE_AGENT) < (K2B / 32))
                __builtin_amdgcn_s_sleep(1);
        }
        if (threadIdx.x == 0)
            __hip_atomic_store(&rel[phase], 1,
                               __ATOMIC_RELAXED, __HIP_MEMORY_SCOPE_AGENT);
    } else {
        if (threadIdx.x == 0) {
            __hip_atomic_fetch_add(&cnt[phase * 1024 + (blockIdx.x & 31) * 32], 1,
                                   __ATOMIC_RELAXED, __HIP_MEMORY_SCOPE_AGENT);
            while (__hip_atomic_load(&rel[phase], __ATOMIC_RELAXED,
                                     __HIP_MEMORY_SCOPE_AGENT) == 0)
                __builtin_amdgcn_s_sleep(2);
        }
    }
    __syncthreads();
}

// ================= K1: csr + mask/barrier-init + gemm tiles ====================
__global__ __launch_bounds__(256) void k1(const float* __restrict__ x,
                                          const float* __restrict__ W0,
                                          const float* __restrict__ adj,
                                          int* __restrict__ deg,
                                          unsigned short* __restrict__ nbr,
                                          const unsigned char* __restrict__ mb,
                                          int* __restrict__ flag,
                                          int* __restrict__ cntrel,
                                          float* __restrict__ hp) {
    __shared__ float sx[BM][SXS];
    __shared__ float sw[CHUNK * HGCN];
    int b = blockIdx.x, t = threadIdx.x;

    if (b < CSRB) {                        // ---- CSR build: 4 waves, 1 row each
        int lane = t & 63;
        int row  = b * 4 + (t >> 6);
        const float*  ar  = adj + (size_t)row * NN;
        const float4* ar4 = (const float4*)ar;
        unsigned short* nb = nbr + (size_t)row * NBS;
        int cnt = 0;
        #pragma unroll
        for (int it = 0; it < 6; ++it) {   // 6*256 = 1536 elements
            float4 v = ar4[it * 64 + lane];
            int base = it * 256 + 4 * lane;
            #pragma unroll
            for (int c = 0; c < 4; ++c) {
                float vc = (c == 0) ? v.x : (c == 1) ? v.y : (c == 2) ? v.z : v.w;
                bool p = (vc != 0.0f);
                unsigned long long m = __ballot(p);
                if (p) {
                    int off = cnt + __popcll(m & ((1ull << lane) - 1ull));
                    if (off < NBS) nb[off] = (unsigned short)(base + c);
                }
                cnt += __popcll(m);
            }
        }
        {                                  // tail 64
            float v = ar[1536 + lane];
            bool p = (v != 0.0f);
            unsigned long long m = __ballot(p);
            if (p) {
                int off = cnt + __popcll(m & ((1ull << lane) - 1ull));
                if (off < NBS) nb[off] = (unsigned short)(1536 + lane);
            }
            cnt += __popcll(m);
        }
        if (lane == 0) deg[row] = cnt < NBS ? cnt : NBS;
        return;
    }

    if (b == CSRB) {                       // ---- barrier init + mask detect
        for (int i = t; i < 4 * 1024 + 8; i += 256) cntrel[i] = 0;
        if (t < 64) {
            int lane = t;
            bool odd = false, flt = false;
            for (int i = lane; i < NN; i += 64) {
                unsigned char v = mb[i];
                if (v) {
                    int r = i & 3;
                    if (r != 0) odd = true;
                    if (r >= 2 && (v == 0x3F || v == 0x80)) flt = true;  // 1.0f pattern
                }
            }
            unsigned long long mo = __ballot(odd);
            unsigned long long mf = __ballot(flt);
            if (lane == 0) *flag = mf ? 2 : (mo ? 1 : 0);  // 2=f32, 1=u8, 0=i32
        }
        return;
    }

    // ---- GEMM tile: h0 partial = x[rb-block] @ W0[k-chunk]
    int tile = b - (CSRB + 1);
    int rb   = tile % RB;
    int ks   = tile / RB;
    int lane = t & 31;
    int row0 = rb * BM;
    int k0   = ks * CHUNK;
    int vk   = FIN - k0; if (vk > CHUNK) vk = CHUNK;

    {
        int g = t >> 5;
        #pragma unroll
        for (int j = 0; j < 4; ++j) {
            int r = g + 8 * j;
            const float* xr = x + (size_t)(row0 + r) * FIN + k0;
            #pragma unroll
            for (int m = 0; m < 3; ++m) {
                int k = lane + 32 * m;
                if (k < CHUNK) sx[r][k] = (k < vk) ? xr[k] : 0.0f;
            }
        }
    }
    {
        const float4* w4  = (const float4*)(W0 + (size_t)k0 * HGCN);
        float4*       sw4 = (float4*)sw;
        int vf4 = vk * 8;
        for (int i = t; i < CHUNK * 8; i += 256)
            sw4[i] = (i < vf4) ? w4[i] : make_float4(0.f, 0.f, 0.f, 0.f);
    }
    __syncthreads();

    int col = lane;
    int rq  = t >> 5;
    float acc0 = 0.f, acc1 = 0.f, acc2 = 0.f, acc3 = 0.f;
    #pragma unroll 4
    for (int kk = 0; kk < 88; kk += 4) {
        float4 a0 = *(const float4*)&sx[rq     ][kk];
        float4 a1 = *(const float4*)&sx[rq +  8][kk];
        float4 a2 = *(const float4*)&sx[rq + 16][kk];
        float4 a3 = *(const float4*)&sx[rq + 24][kk];
        float w0v = sw[(kk + 0) * HGCN + col];
        float w1v = sw[(kk + 1) * HGCN + col];
        float w2v = sw[(kk + 2) * HGCN + col];
        float w3v = sw[(kk + 3) * HGCN + col];
        acc0 += a0.x * w0v + a0.y * w1v + a0.z * w2v + a0.w * w3v;
        acc1 += a1.x * w0v + a1.y * w1v + a1.z * w2v + a1.w * w3v;
        acc2 += a2.x * w0v + a2.y * w1v + a2.z * w2v + a2.w * w3v;
        acc3 += a3.x * w0v + a3.y * w1v + a3.z * w2v + a3.w * w3v;
    }
    #pragma unroll
    for (int kk = 88; kk < CHUNK; ++kk) {
        float wv = sw[kk * HGCN + col];
        acc0 += sx[rq     ][kk] * wv;
        acc1 += sx[rq +  8][kk] * wv;
        acc2 += sx[rq + 16][kk] * wv;
        acc3 += sx[rq + 24][kk] * wv;
    }

    float* o = hp + (size_t)ks * NN * HGCN + (size_t)(row0 + rq) * HGCN + col;
    o[0 * 8 * HGCN] = acc0;
    o[1 * 8 * HGCN] = acc1;
    o[2 * 8 * HGCN] = acc2;
    o[3 * 8 * HGCN] = acc3;
}

// ================= K2 phases ====================================================
// F=32: topk source is h32 only. F=40: cols 0:32 from h32, 32:40 from c1in.
template<int F, int MID>
__device__ __forceinline__ void lgconv_phase(int b, int wave, int lane, int t,
        const int* __restrict__ deg, const unsigned short* __restrict__ nbr,
        const float* __restrict__ Wa, const float* __restrict__ Wb,
        const float* __restrict__ g, const float* __restrict__ bb,
        const float* __restrict__ mm, const float* __restrict__ vv,
        const float* __restrict__ h32, const float* __restrict__ c1in,
        float* __restrict__ outbuf, float* sWa, float* T, float* C1) {
    {                                       // stage Wa (5*F*MID floats, %4==0)
        const float4* w4 = (const float4*)Wa;
        float4*       s4 = (float4*)sWa;
        for (int i = t; i < 5 * F * MID / 4; i += 512) s4[i] = w4[i];
    }
    __syncthreads();

    int row = b * 8 + wave;
    bool act = row < NN;
    int d = 0;
    const unsigned short* nb = nullptr;
    if (act) { d = deg[row]; nb = nbr + (size_t)row * NBS; }

    if (act && lane < F) {                  // topk bubble (8 largest positives)
        float t0=0.f,t1=0.f,t2=0.f,t3=0.f,t4=0.f,t5=0.f,t6=0.f,t7=0.f;
        for (int it = 0; it < d; ++it) {
            int n = nb[it];
            float val;
            if constexpr (F == 32) val = h32[n * HGCN + lane];
            else val = (lane < 32) ? h32[n * HGCN + lane] : c1in[n * 8 + (lane - 32)];
            float c;
            c = t0; t0 = fmaxf(c, val); val = fminf(c, val);
            c = t1; t1 = fmaxf(c, val); val = fminf(c, val);
            c = t2; t2 = fmaxf(c, val); val = fminf(c, val);
            c = t3; t3 = fmaxf(c, val); val = fminf(c, val);
            c = t4; t4 = fmaxf(c, val); val = fminf(c, val);
            c = t5; t5 = fmaxf(c, val); val = fminf(c, val);
            c = t6; t6 = fmaxf(c, val); val = fminf(c, val);
            c = t7; t7 = fmaxf(c, val); val = fminf(c, val);
        }
        float own;
        if constexpr (F == 32) own = h32[row * HGCN + lane];
        else own = (lane < 32) ? h32[row * HGCN + lane] : c1in[row * 8 + (lane - 32)];
        T[0*F+lane] = own;                  // own feature first
        T[1*F+lane] = t0; T[2*F+lane] = t1; T[3*F+lane] = t2; T[4*F+lane] = t3;
        T[5*F+lane] = t4; T[6*F+lane] = t5; T[7*F+lane] = t6; T[8*F+lane] = t7;
    }
    __syncthreads();

    if (act) {                              // conv1
        for (int oi = lane; oi < 5 * MID; oi += 64) {
            int p = oi / MID, o = oi - p * MID;
            float acc = 0.f;
            #pragma unroll
            for (int kw = 0; kw < 5; ++kw) {
                const float* w  = &sWa[kw * F * MID + o];
                const float* tt = &T[(p + kw) * F];
                for (int ci = 0; ci < F; ++ci)
                    acc += tt[ci] * w[ci * MID];
            }
            C1[p * MID + o] = acc;
        }
    }
    __syncthreads();

    if (act && lane < 8) {                  // conv2 pos-0 + BN
        float acc = 0.f;
        #pragma unroll
        for (int kw = 0; kw < 5; ++kw)
            for (int ci = 0; ci < MID; ++ci)
                acc += C1[kw * MID + ci] * Wb[(kw * MID + ci) * 8 + lane];
        float y = g[lane] * (acc - mm[lane]) * rsqrtf(vv[lane] + BN_EPS) + bb[lane];
        astore(&outbuf[row * 8 + lane], y);
    }
}

__global__ __launch_bounds__(512) void k2(
        const int* __restrict__ deg, const unsigned short* __restrict__ nbr,
        const float* __restrict__ hp, float* __restrict__ h0,
        float* __restrict__ h32, float* __restrict__ c1, float* __restrict__ c2,
        const float* __restrict__ W1a, const float* __restrict__ W1b,
        const float* __restrict__ g1, const float* __restrict__ b1,
        const float* __restrict__ m1, const float* __restrict__ v1,
        const float* __restrict__ W2a, const float* __restrict__ W2b,
        const float* __restrict__ g2, const float* __restrict__ b2,
        const float* __restrict__ m2, const float* __restrict__ v2,
        const float* __restrict__ Wout, const void* __restrict__ mask,
        const int* __restrict__ flag, int* __restrict__ cntrel,
        float* __restrict__ out) {
    __shared__ float sWa[4800];             // max(5*32*20, 5*40*24)
    __shared__ float T [8][9 * 40];
    __shared__ float C1s[8][5 * 24];
    __shared__ float sfin[8][HGCN + 16];    // 48 gathered features
    int t = threadIdx.x, b = blockIdx.x;
    int wave = t >> 6, lane = t & 63;
    int* cnt = cntrel;
    int* rel = cntrel + 4 * 1024;

    // ---- phase R: h0 = sum of split-K partials (deterministic order)
    {
        int gid = b * 512 + t;
        if (gid < NN * HGCN) {
            float s = 0.f;
            #pragma unroll
            for (int k = 0; k < KS; ++k) s += hp[(size_t)k * NN * HGCN + gid];
            astore(&h0[gid], s);
        }
    }
    gbar(cnt, rel, 0);

    // ---- phase S: h32 = adj @ h0 (CSR gather, cached reads)
    {
        int grp = b * 16 + (t >> 5);
        if (grp < NN) {
            int f = t & 31;
            int d = deg[grp];
            const unsigned short* nb = nbr + (size_t)grp * NBS;
            float acc = 0.f;
            int it = 0;
            for (; it + 2 <= d; it += 2) {
                int n0 = nb[it], n1 = nb[it + 1];
                acc += h0[n0 * HGCN + f] + h0[n1 * HGCN + f];
            }
            if (it < d) acc += h0[(int)nb[it] * HGCN + f];
            astore(&h32[grp * HGCN + f], acc);
        }
    }
    gbar(cnt, rel, 1);

    lgconv_phase<32, 20>(b, wave, lane, t, deg, nbr, W1a, W1b, g1, b1, m1, v1,
                         h32, nullptr, c1, sWa, T[wave], C1s[wave]);
    gbar(cnt, rel, 2);

    lgconv_phase<40, 24>(b, wave, lane, t, deg, nbr, W2a, W2b, g2, b2, m2, v2,
                         h32, c1, c2, sWa, T[wave], C1s[wave]);
    gbar(cnt, rel, 3);

    // ---- phase F: out = mask * ((adj @ [h32|c1|c2]) @ Wout)
    {
        int row = b * 8 + wave;
        bool act = row < NN;
        int d = 0;
        const unsigned short* nb = nullptr;
        if (act) { d = deg[row]; nb = nbr + (size_t)row * NBS; }
        if (act && lane < 48) {
            float acc = 0.f;
            for (int it = 0; it < d; ++it) {
                int n = nb[it];
                float v;
                if (lane < 32)      v = h32[n * HGCN + lane];
                else if (lane < 40) v = c1[n * 8 + (lane - 32)];
                else                v = c2[n * 8 + (lane - 40)];
                acc += v;
            }
            sfin[wave][lane] = acc;
        }
        __syncthreads();
        if (act && lane < 7) {
            float acc = 0.f;
            #pragma unroll
            for (int k = 0; k < 48; ++k) acc += sfin[wave][k] * Wout[k * 7 + lane];
            int fl = *flag;
            bool mk;
            if (fl == 2)      mk = ((const float*)mask)[row] != 0.0f;
            else if (fl == 1) mk = ((const unsigned char*)mask)[row] != 0;
            else              mk = ((const int*)mask)[row] != 0;
            out[row * 7 + lane] = mk ? acc : 0.0f;
        }
    }
}

extern "C" void kernel_launch(void* const* d_in, const int* in_sizes, int n_in,
                              void* d_out, int out_size, void* d_ws, size_t ws_size,
                              hipStream_t stream) {
    const float* x    = (const float*)d_in[0];
    const float* adj  = (const float*)d_in[1];
    const float* W0   = (const float*)d_in[2];
    const float* W1a  = (const float*)d_in[3];
    const float* W1b  = (const float*)d_in[4];
    const float* W2a  = (const float*)d_in[5];
    const float* W2b  = (const float*)d_in[6];
    const float* Wout = (const float*)d_in[7];
    const float* g1 = (const float*)d_in[8];
    const float* b1 = (const float*)d_in[9];
    const float* m1 = (const float*)d_in[10];
    const float* v1 = (const float*)d_in[11];
    const float* g2 = (const float*)d_in[12];
    const float* b2 = (const float*)d_in[13];
    const float* m2 = (const float*)d_in[14];
    const float* v2 = (const float*)d_in[15];
    const void*  mask = d_in[16];

    char* ws = (char*)d_ws;
    int*            flag   = (int*)(ws + 0);
    int*            cntrel = (int*)(ws + 4096);             // 4*1024+8 ints (~16.4 KB)
    int*            deg    = (int*)(ws + 24576);            // 6400 B
    unsigned short* nbr    = (unsigned short*)(ws + 32768); // 307200 B
    float*          h0     = (float*)(ws + 339968);         // 204800 B
    float*          h32    = (float*)(ws + 544768);         // 204800 B
    float*          c1     = (float*)(ws + 749568);         // 51200 B
    float*          c2     = (float*)(ws + 800768);         // 51200 B
    float*          hp     = (float*)(ws + 851968);         // 3.3 MB

    float* out = (float*)d_out;

    k1<<<K1B, 256, 0, stream>>>(x, W0, adj, deg, nbr,
                                (const unsigned char*)mask, flag, cntrel, hp);
    k2<<<K2B, 512, 0, stream>>>(deg, nbr, hp, h0, h32, c1, c2,
                                W1a, W1b, g1, b1, m1, v1,
                                W2a, W2b, g2, b2, m2, v2,
                                Wout, mask, flag, cntrel, out);
}

// Round 11
// 60.671 us; speedup vs baseline: 5.8789x; 1.1981x over previous
//
#include <hip/hip_runtime.h>
#include <hip/hip_bf16.h>

// LGCN on MI355X, 2-launch version. N=1600, Fin=1433, GCN hidden=32,
// two LGConv blocks (+8 ch each), out 7 channels, row mask.
// K1: CSR build + mask detect + barrier init + split-K GEMM (all independent).
// K2: reduce -> spmv -> lgconv1 -> lgconv2 -> final.
//   Cross-block writes: agent-scope relaxed atomic stores (sc1 -> MALL).
//   Cross-block reads:  normal cached loads (validated R10: value-stable replays).
//   Grid barrier: 32-slot strided arrival counters + single release flag.
//   R11: 8-deep gather pipelines, all-block striping, hp [row][col][ks] layout.

constexpr int NN   = 1600;
constexpr int FIN  = 1433;
constexpr int HGCN = 32;
constexpr int NBS  = 96;    // CSR neighbor stride
constexpr float BN_EPS = 1e-3f;

constexpr int KS    = 16;
constexpr int CHUNK = 90;   // 16*90 = 1440 >= 1433
constexpr int BM    = 32;
constexpr int SXS   = 92;
constexpr int RB    = NN / BM;            // 50 row-blocks
constexpr int CSRB  = 400;                // csr blocks (4 rows each)
constexpr int K1B   = CSRB + 1 + RB * KS; // 1201
constexpr int K2B   = 256;                // <= #CUs (LDS 36KB -> co-resident)

// ---------------- agent-coherent (cross-XCD) store -----------------------------
__device__ __forceinline__ void astore(float* p, float v) {
    __hip_atomic_store(p, v, __ATOMIC_RELAXED, __HIP_MEMORY_SCOPE_AGENT);
}

// ---------------- tree grid barrier (no fences, spread arrivals) ---------------
__device__ __forceinline__ void gbar(int* cnt, int* rel, int phase) {
    __syncthreads();
    if (blockIdx.x == 0) {
        if (threadIdx.x == 0)
            __hip_atomic_fetch_add(&cnt[phase * 1024], 1,
                                   __ATOMIC_RELAXED, __HIP_MEMORY_SCOPE_AGENT);
        if (threadIdx.x < 32) {
            int* slot = &cnt[phase * 1024 + threadIdx.x * 32];
            while (__hip_atomic_load(slot, __ATOMIC_RELAXED,
                                     __HIP_MEMORY_SCOPE_AGENT) < (K2B / 32))
                __builtin_amdgcn_s_sleep(1);
        }
        if (threadIdx.x == 0)
            __hip_atomic_store(&rel[phase], 1,
                               __ATOMIC_RELAXED, __HIP_MEMORY_SCOPE_AGENT);
    } else {
        if (threadIdx.x == 0) {
            __hip_atomic_fetch_add(&cnt[phase * 1024 + (blockIdx.x & 31) * 32], 1,
                                   __ATOMIC_RELAXED, __HIP_MEMORY_SCOPE_AGENT);
            while (__hip_atomic_load(&rel[phase], __ATOMIC_RELAXED,
                                     __HIP_MEMORY_SCOPE_AGENT) == 0)
                __builtin_amdgcn_s_sleep(1);
        }
    }
    __syncthreads();
}

// ================= K1: csr + mask/barrier-init + gemm tiles ====================
__global__ __launch_bounds__(256) void k1(const float* __restrict__ x,
                                          const float* __restrict__ W0,
                                          const float* __restrict__ adj,
                                          int* __restrict__ deg,
                                          unsigned short* __restrict__ nbr,
                                          const unsigned char* __restrict__ mb,
                                          int* __restrict__ flag,
                                          int* __restrict__ cntrel,
                                          float* __restrict__ hp) {
    __shared__ float sx[BM][SXS];
    __shared__ float sw[CHUNK * HGCN];
    int b = blockIdx.x, t = threadIdx.x;

    if (b < CSRB) {                        // ---- CSR build: 4 waves, 1 row each
        int lane = t & 63;
        int row  = b * 4 + (t >> 6);
        const float*  ar  = adj + (size_t)row * NN;
        const float4* ar4 = (const float4*)ar;
        unsigned short* nb = nbr + (size_t)row * NBS;
        int cnt = 0;
        #pragma unroll
        for (int it = 0; it < 6; ++it) {   // 6*256 = 1536 elements
            float4 v = ar4[it * 64 + lane];
            int base = it * 256 + 4 * lane;
            #pragma unroll
            for (int c = 0; c < 4; ++c) {
                float vc = (c == 0) ? v.x : (c == 1) ? v.y : (c == 2) ? v.z : v.w;
                bool p = (vc != 0.0f);
                unsigned long long m = __ballot(p);
                if (p) {
                    int off = cnt + __popcll(m & ((1ull << lane) - 1ull));
                    if (off < NBS) nb[off] = (unsigned short)(base + c);
                }
                cnt += __popcll(m);
            }
        }
        {                                  // tail 64
            float v = ar[1536 + lane];
            bool p = (v != 0.0f);
            unsigned long long m = __ballot(p);
            if (p) {
                int off = cnt + __popcll(m & ((1ull << lane) - 1ull));
                if (off < NBS) nb[off] = (unsigned short)(1536 + lane);
            }
            cnt += __popcll(m);
        }
        if (lane == 0) deg[row] = cnt < NBS ? cnt : NBS;
        return;
    }

    if (b == CSRB) {                       // ---- barrier init + mask detect
        for (int i = t; i < 4 * 1024 + 8; i += 256) cntrel[i] = 0;
        if (t < 64) {
            int lane = t;
            bool odd = false, flt = false;
            for (int i = lane; i < NN; i += 64) {
                unsigned char v = mb[i];
                if (v) {
                    int r = i & 3;
                    if (r != 0) odd = true;
                    if (r >= 2 && (v == 0x3F || v == 0x80)) flt = true;  // 1.0f pattern
                }
            }
            unsigned long long mo = __ballot(odd);
            unsigned long long mf = __ballot(flt);
            if (lane == 0) *flag = mf ? 2 : (mo ? 1 : 0);  // 2=f32, 1=u8, 0=i32
        }
        return;
    }

    // ---- GEMM tile: hp[row][col][ks] partial = x[rb-block] @ W0[k-chunk]
    int tile = b - (CSRB + 1);
    int rb   = tile % RB;
    int ks   = tile / RB;
    int lane = t & 31;
    int row0 = rb * BM;
    int k0   = ks * CHUNK;
    int vk   = FIN - k0; if (vk > CHUNK) vk = CHUNK;

    {
        int g = t >> 5;
        #pragma unroll
        for (int j = 0; j < 4; ++j) {
            int r = g + 8 * j;
            const float* xr = x + (size_t)(row0 + r) * FIN + k0;
            #pragma unroll
            for (int m = 0; m < 3; ++m) {
                int k = lane + 32 * m;
                if (k < CHUNK) sx[r][k] = (k < vk) ? xr[k] : 0.0f;
            }
        }
    }
    {
        const float4* w4  = (const float4*)(W0 + (size_t)k0 * HGCN);
        float4*       sw4 = (float4*)sw;
        int vf4 = vk * 8;
        for (int i = t; i < CHUNK * 8; i += 256)
            sw4[i] = (i < vf4) ? w4[i] : make_float4(0.f, 0.f, 0.f, 0.f);
    }
    __syncthreads();

    int col = lane;
    int rq  = t >> 5;
    float acc0 = 0.f, acc1 = 0.f, acc2 = 0.f, acc3 = 0.f;
    #pragma unroll 4
    for (int kk = 0; kk < 88; kk += 4) {
        float4 a0 = *(const float4*)&sx[rq     ][kk];
        float4 a1 = *(const float4*)&sx[rq +  8][kk];
        float4 a2 = *(const float4*)&sx[rq + 16][kk];
        float4 a3 = *(const float4*)&sx[rq + 24][kk];
        float w0v = sw[(kk + 0) * HGCN + col];
        float w1v = sw[(kk + 1) * HGCN + col];
        float w2v = sw[(kk + 2) * HGCN + col];
        float w3v = sw[(kk + 3) * HGCN + col];
        acc0 += a0.x * w0v + a0.y * w1v + a0.z * w2v + a0.w * w3v;
        acc1 += a1.x * w0v + a1.y * w1v + a1.z * w2v + a1.w * w3v;
        acc2 += a2.x * w0v + a2.y * w1v + a2.z * w2v + a2.w * w3v;
        acc3 += a3.x * w0v + a3.y * w1v + a3.z * w2v + a3.w * w3v;
    }
    #pragma unroll
    for (int kk = 88; kk < CHUNK; ++kk) {
        float wv = sw[kk * HGCN + col];
        acc0 += sx[rq     ][kk] * wv;
        acc1 += sx[rq +  8][kk] * wv;
        acc2 += sx[rq + 16][kk] * wv;
        acc3 += sx[rq + 24][kk] * wv;
    }

    // hp[row][col][ks]
    float* o = hp + ((size_t)(row0 + rq) * HGCN + col) * KS + ks;
    o[0 * 8 * HGCN * KS] = acc0;
    o[1 * 8 * HGCN * KS] = acc1;
    o[2 * 8 * HGCN * KS] = acc2;
    o[3 * 8 * HGCN * KS] = acc3;
}

// ================= K2 phases ====================================================
// F=32: topk source is h32 only. F=40: cols 0:32 from h32, 32:40 from c1in.
template<int F, int MID>
__device__ __forceinline__ void lgconv_phase(int b, int wave, int lane, int t,
        const int* __restrict__ deg, const unsigned short* __restrict__ nbr,
        const float* __restrict__ Wa, const float* __restrict__ Wb,
        const float* __restrict__ g, const float* __restrict__ bb,
        const float* __restrict__ mm, const float* __restrict__ vv,
        const float* __restrict__ h32, const float* __restrict__ c1in,
        float* __restrict__ outbuf, float* sWa, float* T, float* C1) {
    {                                       // stage Wa (5*F*MID floats, %4==0)
        const float4* w4 = (const float4*)Wa;
        float4*       s4 = (float4*)sWa;
        for (int i = t; i < 5 * F * MID / 4; i += 512) s4[i] = w4[i];
    }
    __syncthreads();

    int row = b + 256 * wave;               // striped: all blocks busy
    bool act = row < NN;
    int d = 0;
    const unsigned short* nb = nullptr;
    if (act) { d = deg[row]; nb = nbr + (size_t)row * NBS; }

    if (act && lane < F) {                  // topk bubble, 8-deep gather pipeline
        float t0=0.f,t1=0.f,t2=0.f,t3=0.f,t4=0.f,t5=0.f,t6=0.f,t7=0.f;
        #define BUBBLE(val_) { float val=val_, c;                       \
            c = t0; t0 = fmaxf(c, val); val = fminf(c, val);            \
            c = t1; t1 = fmaxf(c, val); val = fminf(c, val);            \
            c = t2; t2 = fmaxf(c, val); val = fminf(c, val);            \
            c = t3; t3 = fmaxf(c, val); val = fminf(c, val);            \
            c = t4; t4 = fmaxf(c, val); val = fminf(c, val);            \
            c = t5; t5 = fmaxf(c, val); val = fminf(c, val);            \
            c = t6; t6 = fmaxf(c, val); val = fminf(c, val);            \
            c = t7; t7 = fmaxf(c, val); val = fminf(c, val); }
        #define LDV(n_) ((F == 32) ? h32[(n_) * HGCN + lane]            \
            : ((lane < 32) ? h32[(n_) * HGCN + lane] : c1in[(n_) * 8 + (lane - 32)]))
        int it = 0;
        for (; it + 8 <= d; it += 8) {
            float v[8];
            #pragma unroll
            for (int j = 0; j < 8; ++j) v[j] = LDV((int)nb[it + j]);
            #pragma unroll
            for (int j = 0; j < 8; ++j) BUBBLE(v[j]);
        }
        for (; it < d; ++it) BUBBLE(LDV((int)nb[it]));
        T[0*F+lane] = LDV(row);             // own feature first
        T[1*F+lane] = t0; T[2*F+lane] = t1; T[3*F+lane] = t2; T[4*F+lane] = t3;
        T[5*F+lane] = t4; T[6*F+lane] = t5; T[7*F+lane] = t6; T[8*F+lane] = t7;
        #undef LDV
        #undef BUBBLE
    }
    __syncthreads();

    if (act) {                              // conv1
        for (int oi = lane; oi < 5 * MID; oi += 64) {
            int p = oi / MID, o = oi - p * MID;
            float acc = 0.f;
            #pragma unroll
            for (int kw = 0; kw < 5; ++kw) {
                const float* w  = &sWa[kw * F * MID + o];
                const float* tt = &T[(p + kw) * F];
                for (int ci = 0; ci < F; ++ci)
                    acc += tt[ci] * w[ci * MID];
            }
            C1[p * MID + o] = acc;
        }
    }
    __syncthreads();

    if (act && lane < 8) {                  // conv2 pos-0 + BN
        float acc = 0.f;
        #pragma unroll
        for (int kw = 0; kw < 5; ++kw)
            for (int ci = 0; ci < MID; ++ci)
                acc += C1[kw * MID + ci] * Wb[(kw * MID + ci) * 8 + lane];
        float y = g[lane] * (acc - mm[lane]) * rsqrtf(vv[lane] + BN_EPS) + bb[lane];
        astore(&outbuf[row * 8 + lane], y);
    }
}

__global__ __launch_bounds__(512) void k2(
        const int* __restrict__ deg, const unsigned short* __restrict__ nbr,
        const float* __restrict__ hp, float* __restrict__ h0,
        float* __restrict__ h32, float* __restrict__ c1, float* __restrict__ c2,
        const float* __restrict__ W1a, const float* __restrict__ W1b,
        const float* __restrict__ g1, const float* __restrict__ b1,
        const float* __restrict__ m1, const float* __restrict__ v1,
        const float* __restrict__ W2a, const float* __restrict__ W2b,
        const float* __restrict__ g2, const float* __restrict__ b2,
        const float* __restrict__ m2, const float* __restrict__ v2,
        const float* __restrict__ Wout, const void* __restrict__ mask,
        const int* __restrict__ flag, int* __restrict__ cntrel,
        float* __restrict__ out) {
    __shared__ float sWa[4800];             // max(5*32*20, 5*40*24)
    __shared__ float T [8][9 * 40];
    __shared__ float C1s[8][5 * 24];
    __shared__ float sfin[8][HGCN + 16];    // 48 gathered features
    int t = threadIdx.x, b = blockIdx.x;
    int wave = t >> 6, lane = t & 63;
    int* cnt = cntrel;
    int* rel = cntrel + 4 * 1024;

    // ---- phase R: h0 = sum of split-K partials, hp[row][col][ks] contiguous
    {
        if (t < 200) {
            int e = b * 200 + t;            // 256*200 = 51200 elements
            const float4* hp4 = (const float4*)(hp + (size_t)e * KS);
            float4 p0 = hp4[0], p1 = hp4[1], p2 = hp4[2], p3 = hp4[3];
            float s = ((p0.x + p0.y) + (p0.z + p0.w)) + ((p1.x + p1.y) + (p1.z + p1.w))
                    + ((p2.x + p2.y) + (p2.z + p2.w)) + ((p3.x + p3.y) + (p3.z + p3.w));
            astore(&h0[e], s);
        }
    }
    gbar(cnt, rel, 0);

    // ---- phase S: h32 = adj @ h0 (CSR gather, 8-deep pipeline, striped)
    {
        int row = b + 256 * (t >> 5);       // 16 half-waves * 256 blocks = 4096 slots
        if (row < NN) {
            int f = t & 31;
            int d = deg[row];
            const unsigned short* nb = nbr + (size_t)row * NBS;
            float acc = 0.f;
            int it = 0;
            for (; it + 8 <= d; it += 8) {
                float v[8];
                #pragma unroll
                for (int j = 0; j < 8; ++j) v[j] = h0[(int)nb[it + j] * HGCN + f];
                #pragma unroll
                for (int j = 0; j < 8; ++j) acc += v[j];
            }
            for (; it < d; ++it) acc += h0[(int)nb[it] * HGCN + f];
            astore(&h32[row * HGCN + f], acc);
        }
    }
    gbar(cnt, rel, 1);

    lgconv_phase<32, 20>(b, wave, lane, t, deg, nbr, W1a, W1b, g1, b1, m1, v1,
                         h32, nullptr, c1, sWa, T[wave], C1s[wave]);
    gbar(cnt, rel, 2);

    lgconv_phase<40, 24>(b, wave, lane, t, deg, nbr, W2a, W2b, g2, b2, m2, v2,
                         h32, c1, c2, sWa, T[wave], C1s[wave]);
    gbar(cnt, rel, 3);

    // ---- phase F: out = mask * ((adj @ [h32|c1|c2]) @ Wout)  (striped)
    {
        int row = b + 256 * wave;
        bool act = row < NN;
        int d = 0;
        const unsigned short* nb = nullptr;
        if (act) { d = deg[row]; nb = nbr + (size_t)row * NBS; }
        if (act && lane < 48) {
            #define LDF(n_) ((lane < 32) ? h32[(n_) * HGCN + lane]      \
                : (lane < 40) ? c1[(n_) * 8 + (lane - 32)]              \
                              : c2[(n_) * 8 + (lane - 40)])
            float acc = 0.f;
            int it = 0;
            for (; it + 8 <= d; it += 8) {
                float v[8];
                #pragma unroll
                for (int j = 0; j < 8; ++j) v[j] = LDF((int)nb[it + j]);
                #pragma unroll
                for (int j = 0; j < 8; ++j) acc += v[j];
            }
            for (; it < d; ++it) acc += LDF((int)nb[it]);
            sfin[wave][lane] = acc;
            #undef LDF
        }
        __syncthreads();
        if (act && lane < 7) {
            float acc = 0.f;
            #pragma unroll
            for (int k = 0; k < 48; ++k) acc += sfin[wave][k] * Wout[k * 7 + lane];
            int fl = *flag;
            bool mk;
            if (fl == 2)      mk = ((const float*)mask)[row] != 0.0f;
            else if (fl == 1) mk = ((const unsigned char*)mask)[row] != 0;
            else              mk = ((const int*)mask)[row] != 0;
            out[row * 7 + lane] = mk ? acc : 0.0f;
        }
    }
}

extern "C" void kernel_launch(void* const* d_in, const int* in_sizes, int n_in,
                              void* d_out, int out_size, void* d_ws, size_t ws_size,
                              hipStream_t stream) {
    const float* x    = (const float*)d_in[0];
    const float* adj  = (const float*)d_in[1];
    const float* W0   = (const float*)d_in[2];
    const float* W1a  = (const float*)d_in[3];
    const float* W1b  = (const float*)d_in[4];
    const float* W2a  = (const float*)d_in[5];
    const float* W2b  = (const float*)d_in[6];
    const float* Wout = (const float*)d_in[7];
    const float* g1 = (const float*)d_in[8];
    const float* b1 = (const float*)d_in[9];
    const float* m1 = (const float*)d_in[10];
    const float* v1 = (const float*)d_in[11];
    const float* g2 = (const float*)d_in[12];
    const float* b2 = (const float*)d_in[13];
    const float* m2 = (const float*)d_in[14];
    const float* v2 = (const float*)d_in[15];
    const void*  mask = d_in[16];

    char* ws = (char*)d_ws;
    int*            flag   = (int*)(ws + 0);
    int*            cntrel = (int*)(ws + 4096);             // 4*1024+8 ints (~16.4 KB)
    int*            deg    = (int*)(ws + 24576);            // 6400 B
    unsigned short* nbr    = (unsigned short*)(ws + 32768); // 307200 B
    float*          h0     = (float*)(ws + 339968);         // 204800 B
    float*          h32    = (float*)(ws + 544768);         // 204800 B
    float*          c1     = (float*)(ws + 749568);         // 51200 B
    float*          c2     = (float*)(ws + 800768);         // 51200 B
    float*          hp     = (float*)(ws + 851968);         // 3.3 MB

    float* out = (float*)d_out;

    k1<<<K1B, 256, 0, stream>>>(x, W0, adj, deg, nbr,
                                (const unsigned char*)mask, flag, cntrel, hp);
    k2<<<K2B, 512, 0, stream>>>(deg, nbr, hp, h0, h32, c1, c2,
                                W1a, W1b, g1, b1, m1, v1,
                                W2a, W2b, g2, b2, m2, v2,
                                Wout, mask, flag, cntrel, out);
}